// Round 4
// baseline (124.529 us; speedup 1.0000x reference)
//
#include <hip/hip_runtime.h>

#define NROWS 8192
#define NSPLIT 8
#define JT (NROWS / NSPLIT)  // 1024 j's per split
#define NITER (JT / 64)      // 16
#define L2E 1.4426950408889634f

typedef __attribute__((ext_vector_type(4))) float f32x4;
typedef __attribute__((ext_vector_type(8))) __bf16 bf16x8;
typedef __attribute__((ext_vector_type(4))) unsigned int u32x4;

__device__ __forceinline__ unsigned short f2bf(float x) {
  unsigned u = __float_as_uint(x);
  u += 0x7fffu + ((u >> 16) & 1u);
  return (unsigned short)(u >> 16);
}

// ---------------------------------------------------------------------------
// Kernel A: Wh = h@W (stored bf16 in MFMA-B-fragment order), src=Wh@a1, dst=Wh@a2
// src/dst pre-scaled by log2(e) so k_attn works in exp2 domain.
// Fragment layout: slot (jc, nt, lane, e) holds Wh[j = 32*jc + 8*(lane>>4) + e][nt*16 + (lane&15)]
// ---------------------------------------------------------------------------
__global__ __launch_bounds__(256) void k_prep(
    const float* __restrict__ h, const float* __restrict__ W,
    const float* __restrict__ a, unsigned short* __restrict__ WhB,
    float* __restrict__ src, float* __restrict__ dst) {
  int i = blockIdx.x * 4 + (threadIdx.x >> 6);  // row
  int lane = threadIdx.x & 63;                  // feature
  const float* hrow = h + (size_t)i * 256;
  float s = 0.f;
#pragma unroll 4
  for (int k = 0; k < 256; k += 4) {
    float4 hv = *(const float4*)(hrow + k);
    s = fmaf(hv.x, W[(k + 0) * 64 + lane], s);
    s = fmaf(hv.y, W[(k + 1) * 64 + lane], s);
    s = fmaf(hv.z, W[(k + 2) * 64 + lane], s);
    s = fmaf(hv.w, W[(k + 3) * 64 + lane], s);
  }
  int nt = lane >> 4, c = lane & 15;
  int gi = (i >> 3) & 3, e = i & 7;
  int idx = ((((i >> 5) * 4 + nt) * 64) + c + 16 * gi) * 8 + e;
  WhB[idx] = f2bf(s);
  float v1 = s * a[lane];
  float v2 = s * a[64 + lane];
#pragma unroll
  for (int d = 32; d; d >>= 1) {
    v1 += __shfl_xor(v1, d);
    v2 += __shfl_xor(v2, d);
  }
  if (lane == 0) {
    src[i] = v1 * L2E;
    dst[i] = v2 * L2E;
  }
}

// ---------------------------------------------------------------------------
// Kernel A2: dmax = max_j dst[j]  (global scalar; 1 block)
// ---------------------------------------------------------------------------
__global__ __launch_bounds__(256) void k_dmax(
    const float* __restrict__ dst, float* __restrict__ dmax) {
  __shared__ float red[4];
  float v = -INFINITY;
  for (int i = threadIdx.x; i < NROWS; i += 256) v = fmaxf(v, dst[i]);
#pragma unroll
  for (int d = 32; d; d >>= 1) v = fmaxf(v, __shfl_xor(v, d));
  if ((threadIdx.x & 63) == 0) red[threadIdx.x >> 6] = v;
  __syncthreads();
  if (threadIdx.x == 0)
    *dmax = fmaxf(fmaxf(red[0], red[1]), fmaxf(red[2], red[3]));
}

// ---------------------------------------------------------------------------
// Kernel B: fused masked-softmax + PV, split along j into NSPLIT partials.
// One wave = one (16-row M-tile, split) task. Absolute reference
// Mi = lrelu(src_i + dmax) >= all scores of row i  =>  P = 2^(ev-Mi) <= 1:
// no online max, no rescale, no cross-lane ops in the loop.
// VMEM issue order per iter t: [B(t) L2] [adj(t+1) HBM, youngest].
// EC waits adj(t)=oldest (B+adj(t+1) stay in flight); MFMA waits B(t)
// (adj(t+1) stays in flight). dst comes from LDS (shared per block).
// Full unroll => pure register rotation, no copy-forced vmcnt(0) drains.
// ---------------------------------------------------------------------------
__global__ __launch_bounds__(256, 4) void k_attn(
    const int* __restrict__ adj, const unsigned short* __restrict__ WhB,
    const float* __restrict__ src, const float* __restrict__ dst,
    const float* __restrict__ dmax,
    float* __restrict__ pl, float* __restrict__ pacc) {
  __shared__ float ldst[JT];
  int task = blockIdx.x * 4 + (threadIdx.x >> 6);  // 0 .. 512*NSPLIT-1
  int sp = task >> 9;                              // split (same for whole block)
  int mt = task & 511;                             // M-tile index
  int lane = threadIdx.x & 63;
  int r = lane & 15;  // row within tile / C col
  int g = lane >> 4;  // k-slot group
  int row0 = mt * 16;
  int jbase = sp * JT;

  // stage this split's dst slice to LDS (block-shared)
  for (int k = threadIdx.x; k < JT; k += 256) ldst[k] = dst[jbase + k];
  __syncthreads();

  float srcr = src[row0 + r];
  float dmv = *dmax;
  float vB = srcr + dmv;
  float Mi = fmaxf(vB, 0.2f * vB);  // upper bound on this row's scores

  float lrow = 0.f;
  f32x4 acc[4] = {f32x4{0.f, 0.f, 0.f, 0.f}, f32x4{0.f, 0.f, 0.f, 0.f},
                  f32x4{0.f, 0.f, 0.f, 0.f}, f32x4{0.f, 0.f, 0.f, 0.f}};
  const int* adjp = adj + (size_t)(row0 + r) * NROWS + jbase + 8 * g;
  const bf16x8* Bfr = (const bf16x8*)WhB;

  int4 ab[2][4];
  // prologue: adj(0) in flight
  ab[0][0] = *(const int4*)(adjp + 0);
  ab[0][1] = *(const int4*)(adjp + 4);
  ab[0][2] = *(const int4*)(adjp + 32);
  ab[0][3] = *(const int4*)(adjp + 36);

#pragma unroll
  for (int it = 0; it < NITER; ++it) {
    const int jb = it * 64;
    const int cur = it & 1, nxt = cur ^ 1;

    // --- B(t): L2, issued first (older than adj(t+1))
    int jc = (jbase + jb) >> 5;
    const bf16x8* bp = Bfr + (size_t)jc * 256 + lane;
    bf16x8 b0 = bp[0];
    bf16x8 b1 = bp[64];
    bf16x8 b2 = bp[128];
    bf16x8 b3 = bp[192];
    bf16x8 b4 = bp[256];
    bf16x8 b5 = bp[320];
    bf16x8 b6 = bp[384];
    bf16x8 b7 = bp[448];
    __builtin_amdgcn_sched_barrier(0);

    // --- adj(t+1): HBM, youngest in queue; never force-drained
    const int* ap = adjp + ((it < NITER - 1) ? jb + 64 : 0);
    ab[nxt][0] = *(const int4*)(ap + 0);
    ab[nxt][1] = *(const int4*)(ap + 4);
    ab[nxt][2] = *(const int4*)(ap + 32);
    ab[nxt][3] = *(const int4*)(ap + 36);
    __builtin_amdgcn_sched_barrier(0);

    // --- dst from LDS (4 addresses per wave -> broadcast, conflict-free)
    const float4* dl = (const float4*)(ldst + jb + 8 * g);
    float4 d0 = dl[0];
    float4 d1 = dl[1];
    const float4* dl2 = (const float4*)(ldst + jb + 32 + 8 * g);
    float4 d2 = dl2[0];
    float4 d3 = dl2[1];

    // --- scores -> p (consumes adj(t): waits vmcnt leaving B+adj(t+1))
    float p[16];
#define PE(P, AA, DD)                     \
  {                                       \
    float v_ = srcr + (DD);               \
    v_ = fmaxf(v_, 0.2f * v_);            \
    float e_ = exp2f(v_ - Mi);            \
    (P) = ((AA) > 0) ? e_ : 0.f;          \
  }
    PE(p[0], ab[cur][0].x, d0.x) PE(p[1], ab[cur][0].y, d0.y)
    PE(p[2], ab[cur][0].z, d0.z) PE(p[3], ab[cur][0].w, d0.w)
    PE(p[4], ab[cur][1].x, d1.x) PE(p[5], ab[cur][1].y, d1.y)
    PE(p[6], ab[cur][1].z, d1.z) PE(p[7], ab[cur][1].w, d1.w)
    PE(p[8], ab[cur][2].x, d2.x) PE(p[9], ab[cur][2].y, d2.y)
    PE(p[10], ab[cur][2].z, d2.z) PE(p[11], ab[cur][2].w, d2.w)
    PE(p[12], ab[cur][3].x, d3.x) PE(p[13], ab[cur][3].y, d3.y)
    PE(p[14], ab[cur][3].z, d3.z) PE(p[15], ab[cur][3].w, d3.w)
#undef PE

    unsigned q[8];
#pragma unroll
    for (int t = 0; t < 16; t += 2) {
      lrow += p[t] + p[t + 1];
      unsigned qq;
      asm("v_cvt_pk_bf16_f32 %0, %1, %2" : "=v"(qq) : "v"(p[t]), "v"(p[t + 1]));
      q[t >> 1] = qq;
    }
    u32x4 qv0 = {q[0], q[1], q[2], q[3]};
    u32x4 qv1 = {q[4], q[5], q[6], q[7]};
    bf16x8 A0 = __builtin_bit_cast(bf16x8, qv0);
    bf16x8 A1 = __builtin_bit_cast(bf16x8, qv1);

    // --- MFMA consumes B(t); counted wait leaves adj(t+1) in flight
    __builtin_amdgcn_s_setprio(1);
    acc[0] = __builtin_amdgcn_mfma_f32_16x16x32_bf16(A0, b0, acc[0], 0, 0, 0);
    acc[1] = __builtin_amdgcn_mfma_f32_16x16x32_bf16(A0, b1, acc[1], 0, 0, 0);
    acc[2] = __builtin_amdgcn_mfma_f32_16x16x32_bf16(A0, b2, acc[2], 0, 0, 0);
    acc[3] = __builtin_amdgcn_mfma_f32_16x16x32_bf16(A0, b3, acc[3], 0, 0, 0);
    acc[0] = __builtin_amdgcn_mfma_f32_16x16x32_bf16(A1, b4, acc[0], 0, 0, 0);
    acc[1] = __builtin_amdgcn_mfma_f32_16x16x32_bf16(A1, b5, acc[1], 0, 0, 0);
    acc[2] = __builtin_amdgcn_mfma_f32_16x16x32_bf16(A1, b6, acc[2], 0, 0, 0);
    acc[3] = __builtin_amdgcn_mfma_f32_16x16x32_bf16(A1, b7, acc[3], 0, 0, 0);
    __builtin_amdgcn_s_setprio(0);
  }

  // row-sum of l across the 4 g-groups (lanes r, r+16, r+32, r+48)
  lrow += __shfl_xor(lrow, 16);
  lrow += __shfl_xor(lrow, 32);
  if (lane < 16) pl[sp * NROWS + row0 + lane] = lrow;
#pragma unroll
  for (int nt = 0; nt < 4; nt++)
#pragma unroll
    for (int q2 = 0; q2 < 4; q2++)
      pacc[((size_t)sp * NROWS + row0 + 4 * g + q2) * 64 + nt * 16 + r] = acc[nt][q2];
}

// ---------------------------------------------------------------------------
// Kernel C: combine = plain sums (all splits share the same reference Mi).
// ---------------------------------------------------------------------------
__global__ __launch_bounds__(256) void k_comb(
    const float* __restrict__ pl, const float* __restrict__ pacc,
    float* __restrict__ out) {
  int t = blockIdx.x * 256 + threadIdx.x;
  int row = t >> 6, f = t & 63;
  float L = 0.f, o = 0.f;
#pragma unroll
  for (int s2 = 0; s2 < NSPLIT; s2++) {
    L += pl[s2 * NROWS + row];
    o += pacc[((size_t)s2 * NROWS + row) * 64 + f];
  }
  out[t] = o / L;
}

extern "C" void kernel_launch(void* const* d_in, const int* in_sizes, int n_in,
                              void* d_out, int out_size, void* d_ws, size_t ws_size,
                              hipStream_t stream) {
  const float* h = (const float*)d_in[0];
  const float* W = (const float*)d_in[1];
  const float* a = (const float*)d_in[2];
  const int* adj = (const int*)d_in[3];
  float* out = (float*)d_out;

  char* ws = (char*)d_ws;
  unsigned short* WhB = (unsigned short*)ws;           // 1 MB
  float* src = (float*)(ws + 0x100000);                // 32 KB
  float* dst = (float*)(ws + 0x108000);                // 32 KB
  float* dmax = (float*)(ws + 0x110000);               // 256 B
  float* pl = (float*)(ws + 0x110100);                 // 256 KB
  float* pacc = (float*)(ws + 0x150100);               // 16 MB

  hipLaunchKernelGGL(k_prep, dim3(NROWS / 4), dim3(256), 0, stream, h, W, a, WhB, src, dst);
  hipLaunchKernelGGL(k_dmax, dim3(1), dim3(256), 0, stream, dst, dmax);
  hipLaunchKernelGGL(k_attn, dim3(512 * NSPLIT / 4), dim3(256), 0, stream,
                     adj, WhB, src, dst, dmax, pl, pacc);
  hipLaunchKernelGGL(k_comb, dim3(NROWS * 64 / 256), dim3(256), 0, stream, pl, pacc, out);
}